// Round 2
// 1516.784 us; speedup vs baseline: 1.9234x; 1.9234x over previous
//
#include <hip/hip_runtime.h>
#include <hip/hip_bf16.h>

typedef __bf16 bf16;
typedef __attribute__((ext_vector_type(8))) __bf16 bf16x8;
typedef __attribute__((ext_vector_type(4))) float f32x4;

// Pack two f32x4 into a bf16x8 MFMA fragment (round-to-nearest via cast).
static __device__ inline bf16x8 pack_bf16x8(f32x4 lo, f32x4 hi) {
    bf16x8 t;
#pragma unroll
    for (int j = 0; j < 4; ++j) {
        t[j]     = (__bf16)lo[j];
        t[4 + j] = (__bf16)hi[j];
    }
    return t;
}

// ---------------------------------------------------------------------------
// CSR build (counting sort by destination). 4-byte-granularity traffic only.
// NOTE: all initialization is done by KERNELS (not hipMemsetAsync) so every
// step is unambiguously captured + replayed by graph capture: each call
// rebuilds the CSR from scratch regardless of prior workspace state.
// ---------------------------------------------------------------------------

__global__ __launch_bounds__(256)
void zero_kernel(int* __restrict__ p, int n) {
    int i = blockIdx.x * 256 + threadIdx.x;
    if (i < n) p[i] = 0;
}

// ofs[d+1] += 1 per edge (ofs zeroed by zero_kernel; length nd+1).
__global__ __launch_bounds__(256)
void hist_kernel(const int* __restrict__ di, int* __restrict__ ofs, int E) {
    int i = blockIdx.x * 256 + threadIdx.x;
    int stride = gridDim.x * 256;
    for (; i < E; i += stride) atomicAdd(&ofs[di[i] + 1], 1);
}

// Inclusive scan, stage 1: per-block (2048 elems) scan + block totals.
__global__ __launch_bounds__(256)
void scan_blocks(int* __restrict__ a, int n, int* __restrict__ bsum) {
    __shared__ int lds[256];
    int t = threadIdx.x;
    int base = blockIdx.x * 2048 + t * 8;
    int v[8];
    int run = 0;
#pragma unroll
    for (int j = 0; j < 8; ++j) {
        int idx = base + j;
        int x = (idx < n) ? a[idx] : 0;
        run += x;
        v[j] = run;
    }
    lds[t] = run;
    __syncthreads();
#pragma unroll
    for (int off = 1; off < 256; off <<= 1) {
        int x = (t >= off) ? lds[t - off] : 0;
        __syncthreads();
        lds[t] += x;
        __syncthreads();
    }
    int excl = t ? lds[t - 1] : 0;
#pragma unroll
    for (int j = 0; j < 8; ++j) {
        int idx = base + j;
        if (idx < n) a[idx] = v[j] + excl;
    }
    if (t == 255) bsum[blockIdx.x] = lds[255];
}

// Stage 2: exclusive scan of block totals (single block, carry loop).
__global__ __launch_bounds__(256)
void scan_bsums(int* __restrict__ bsum, int nb) {
    __shared__ int lds[256];
    int t = threadIdx.x;
    int carry = 0;
    for (int base = 0; base < nb; base += 256) {
        int i = base + t;
        int v = (i < nb) ? bsum[i] : 0;
        lds[t] = v;
        __syncthreads();
#pragma unroll
        for (int off = 1; off < 256; off <<= 1) {
            int x = (t >= off) ? lds[t - off] : 0;
            __syncthreads();
            lds[t] += x;
            __syncthreads();
        }
        int excl = t ? lds[t - 1] : 0;
        if (i < nb) bsum[i] = excl + carry;
        carry += lds[255];
        __syncthreads();
    }
}

// Stage 3: add block offsets; also init per-row tickets tick[d] = start(d).
__global__ __launch_bounds__(256)
void scan_add(int* __restrict__ a, int n, const int* __restrict__ bsum,
              int* __restrict__ tick, int nd) {
    int i = blockIdx.x * 256 + threadIdx.x;
    if (i < n) {
        int v = a[i] + bsum[i >> 11];
        a[i] = v;
        if (i < nd) tick[i] = v;
    }
}

// Ticketed bucket fill: esrc[slot] = source id, grouped by destination.
// pos is clamped so no state (even corrupt/poisoned) can cause an OOB write.
__global__ __launch_bounds__(256)
void fill_kernel(const int* __restrict__ si, const int* __restrict__ di,
                 int* __restrict__ tick, int* __restrict__ esrc, int E) {
    int i = blockIdx.x * 256 + threadIdx.x;
    int stride = gridDim.x * 256;
    for (; i < E; i += stride) {
        int pos = atomicAdd(&tick[di[i]], 1);
        pos = pos < 0 ? 0 : (pos >= E ? E - 1 : pos);  // healthy path: no-op
        esrc[pos] = si[i];
    }
}

// ---------------------------------------------------------------------------
// Fused: out_row = L2norm( x_dst@WL^T + b + mean_{e in CSR row}(x_src[e])@WR^T ).
// Block = 4 waves; wave handles 16 rows x 128 cols via 8 col-tiles of
// mfma_f32_16x16x32_bf16 (shared accumulator chains both GEMMs).
// A2 (mean aggregation) is built in registers: lane (m,q) walks row m's edge
// list and accumulates exactly its fragment's 32 floats. No agg buffer, no
// fp32 atomics, no memset. All CSR-derived indices are clamped (defense in
// depth: bounded reads regardless of workspace state).
// ---------------------------------------------------------------------------
__global__ __launch_bounds__(256)
void sage_gemm_fused(const float* __restrict__ xdst,
                     const float* __restrict__ xsrc,
                     const int* __restrict__ ofs,
                     const int* __restrict__ esrc,
                     const float* __restrict__ wl,
                     const float* __restrict__ wr,
                     const float* __restrict__ bias,
                     float* __restrict__ outp,
                     int nd, int nsrc, int Etot, int accumulate) {
    int lane = threadIdx.x & 63;
    int wave = threadIdx.x >> 6;
    int m = lane & 15;   // A row within tile / C col within tile
    int q = lane >> 4;   // quad
    int r0 = blockIdx.x * 64 + wave * 16;   // row base
    int rl = min(r0 + m, nd - 1);           // clamped load row

    // A1 fragments: x_dst rows (fp32 -> bf16). A[m][k=kc*32+q*8+j]
    bf16x8 a1[4];
    const f32x4* xrow = (const f32x4*)(xdst + (size_t)rl * 128);
#pragma unroll
    for (int kc = 0; kc < 4; ++kc)
        a1[kc] = pack_bf16x8(xrow[kc * 8 + q * 2], xrow[kc * 8 + q * 2 + 1]);

    // A2 fragments: in-register CSR mean aggregation. Each lane gathers only
    // its fragment's columns (q*8 .. q*8+7 of each 32-wide k-chunk).
    int start = ofs[rl];
    int end   = ofs[rl + 1];
    start = start < 0 ? 0 : (start > Etot ? Etot : start);
    end   = end < start ? start : (end > Etot ? Etot : end);
    f32x4 aglo[4], aghi[4];
#pragma unroll
    for (int kc = 0; kc < 4; ++kc) {
        aglo[kc] = (f32x4){0.f, 0.f, 0.f, 0.f};
        aghi[kc] = (f32x4){0.f, 0.f, 0.f, 0.f};
    }
    for (int e = start; e < end; ++e) {
        int s = esrc[e];
        s = s < 0 ? 0 : (s >= nsrc ? nsrc - 1 : s);  // healthy path: no-op
        const f32x4* srow = (const f32x4*)(xsrc + (size_t)s * 128 + q * 8);
#pragma unroll
        for (int kc = 0; kc < 4; ++kc) {
            aglo[kc] += srow[kc * 8];
            aghi[kc] += srow[kc * 8 + 1];
        }
    }
    float invc = 1.0f / (float)max(end - start, 1);
    bf16x8 a2[4];
#pragma unroll
    for (int kc = 0; kc < 4; ++kc) {
        bf16x8 t;
#pragma unroll
        for (int j = 0; j < 4; ++j) {
            t[j]     = (__bf16)(aglo[kc][j] * invc);
            t[4 + j] = (__bf16)(aghi[kc][j] * invc);
        }
        a2[kc] = t;
    }

    // 8 col-tiles; B[k][n] = W[n][k]: lane reads W row (n = ct*16+m)
    f32x4 acc[8];
#pragma unroll
    for (int ct = 0; ct < 8; ++ct) {
        f32x4 c = {0.f, 0.f, 0.f, 0.f};
        const f32x4* wlr = (const f32x4*)(wl + (size_t)(ct * 16 + m) * 128);
        const f32x4* wrr = (const f32x4*)(wr + (size_t)(ct * 16 + m) * 128);
#pragma unroll
        for (int kc = 0; kc < 4; ++kc) {
            bf16x8 bl = pack_bf16x8(wlr[kc * 8 + q * 2], wlr[kc * 8 + q * 2 + 1]);
            bf16x8 br = pack_bf16x8(wrr[kc * 8 + q * 2], wrr[kc * 8 + q * 2 + 1]);
            c = __builtin_amdgcn_mfma_f32_16x16x32_bf16(a1[kc], bl, c, 0, 0, 0);
            c = __builtin_amdgcn_mfma_f32_16x16x32_bf16(a2[kc], br, c, 0, 0, 0);
        }
        acc[ct] = c;
    }

    // Epilogue: +bias, per-row L2 norm (row lives across a 16-lane group),
    // normalize, store fp32 (optionally accumulating previous sage's output).
    float ss[4] = {0.f, 0.f, 0.f, 0.f};
#pragma unroll
    for (int ct = 0; ct < 8; ++ct) {
        float bb = bias[ct * 16 + m];
#pragma unroll
        for (int r = 0; r < 4; ++r) {
            float v = acc[ct][r] + bb;
            acc[ct][r] = v;
            ss[r] += v * v;
        }
    }
#pragma unroll
    for (int off = 1; off < 16; off <<= 1) {
#pragma unroll
        for (int r = 0; r < 4; ++r) ss[r] += __shfl_xor(ss[r], off);
    }
    float sc[4];
#pragma unroll
    for (int r = 0; r < 4; ++r) sc[r] = 1.0f / fmaxf(sqrtf(ss[r]), 1e-12f);

#pragma unroll
    for (int r = 0; r < 4; ++r) {
        int orow = r0 + q * 4 + r;  // C/D: row = quad*4 + reg
        if (orow < nd) {
            size_t base = (size_t)orow * 128 + m;
#pragma unroll
            for (int ct = 0; ct < 8; ++ct) {
                float v = acc[ct][r] * sc[r];
                size_t idx = base + (size_t)ct * 16;
                if (accumulate) v += outp[idx];
                outp[idx] = v;
            }
        }
    }
}

extern "C" void kernel_launch(void* const* d_in, const int* in_sizes, int n_in,
                              void* d_out, int out_size, void* d_ws, size_t ws_size,
                              hipStream_t stream) {
    const int D = 128;
    const float* x_article = (const float*)d_in[0];
    const float* x_entity  = (const float*)d_in[1];
    const float* x_fact    = (const float*)d_in[2];
    int NA = in_sizes[0] / D;
    int NE = in_sizes[1] / D;
    int NF = in_sizes[2] / D;

    const int* si[5];
    const int* di[5];
    for (int i = 0; i < 5; ++i) {
        si[i] = (const int*)d_in[3 + 2 * i];
        di[i] = (const int*)d_in[4 + 2 * i];
    }
    const float *wl[5], *bia[5], *wr[5];
    for (int i = 0; i < 5; ++i) {
        wl[i]  = (const float*)d_in[13 + 3 * i];
        bia[i] = (const float*)d_in[14 + 3 * i];
        wr[i]  = (const float*)d_in[15 + 3 * i];
    }

    float* outp = (float*)d_out;
    float* out_article = outp;
    float* out_entity  = outp + (size_t)NA * D;
    float* out_fact    = outp + (size_t)(NA + NE) * D;

    // EDGE_TYPES: (art->ent), (art->fact), (ent->art), (ent->fact), (fact->ent)
    const float* xsrc[5] = {x_article, x_article, x_entity, x_entity, x_fact};
    const float* xdst[5] = {x_entity, x_fact, x_article, x_fact, x_entity};
    int nsrcs[5]   = {NA, NA, NE, NE, NF};
    int ndst[5]    = {NE, NF, NA, NF, NE};
    float* outs[5] = {out_entity, out_fact, out_article, out_fact, out_entity};
    int accs[5]    = {0, 0, 0, 1, 1};

    // Workspace layout per edge type (reused sequentially):
    //   ofs[nd+1] | tick[nd] | esrc[E] | bsum[nb]
    // Max need ~3.2 MB; ws proved >= ~103 MB by the previous (un-chunked
    // scatter) version.
    for (int t = 0; t < 5; ++t) {
        int nd = ndst[t];
        int E  = in_sizes[3 + 2 * t];
        int n1 = nd + 1;
        int* ofs  = (int*)d_ws;
        int* tick = ofs + n1;
        int* esrc = tick + nd;
        int* bsum = esrc + E;

        zero_kernel<<<(n1 + 255) / 256, 256, 0, stream>>>(ofs, n1);
        hist_kernel<<<1024, 256, 0, stream>>>(di[t], ofs, E);
        int nb = (n1 + 2047) / 2048;
        scan_blocks<<<nb, 256, 0, stream>>>(ofs, n1, bsum);
        scan_bsums<<<1, 256, 0, stream>>>(bsum, nb);
        scan_add<<<(n1 + 255) / 256, 256, 0, stream>>>(ofs, n1, bsum, tick, nd);
        fill_kernel<<<1024, 256, 0, stream>>>(si[t], di[t], tick, esrc, E);

        int gblocks = (nd + 63) / 64;
        sage_gemm_fused<<<gblocks, 256, 0, stream>>>(xdst[t], xsrc[t], ofs, esrc,
                                                     wl[t], wr[t], bia[t],
                                                     outs[t], nd, nsrcs[t], E, accs[t]);
    }
}

// Round 3
// 979.479 us; speedup vs baseline: 2.9784x; 1.5486x over previous
//
#include <hip/hip_runtime.h>
#include <hip/hip_bf16.h>

typedef __bf16 bf16;
typedef __attribute__((ext_vector_type(8))) __bf16 bf16x8;
typedef __attribute__((ext_vector_type(4))) float f32x4;

// Pack two f32x4 into a bf16x8 MFMA fragment (round-to-nearest via cast).
static __device__ inline bf16x8 pack_bf16x8(f32x4 lo, f32x4 hi) {
    bf16x8 t;
#pragma unroll
    for (int j = 0; j < 4; ++j) {
        t[j]     = (__bf16)lo[j];
        t[4 + j] = (__bf16)hi[j];
    }
    return t;
}

// ---------------------------------------------------------------------------
// Weight pre-conversion: fp32 W[128][128] -> bf16 fragments laid out so a
// sage wave's B-fragment load is ONE coalesced 16B bf16x8 load:
//   frag[mat][ct][kc][q][m] = W[ct*16+m][kc*32+q*8 .. +7]
// 64 KB per edge type (WL+WR). Kills per-wave fp32->bf16 packing entirely.
// ---------------------------------------------------------------------------
struct WConvArgs { const float* w[10]; bf16* dst; };

__global__ __launch_bounds__(256)
void convert_w(WConvArgs A) {
    int mat = blockIdx.y;                       // 0..9 = (type*2 + {wl,wr})
    int tid = blockIdx.x * 256 + threadIdx.x;   // 0..2047
    if (tid >= 2048) return;
    int m  = tid & 15;
    int q  = (tid >> 4) & 3;
    int kc = (tid >> 6) & 3;
    int ct = tid >> 8;
    const float* src = A.w[mat] + (size_t)(ct * 16 + m) * 128 + kc * 32 + q * 8;
    bf16x8 t;
#pragma unroll
    for (int j = 0; j < 8; ++j) t[j] = (__bf16)src[j];
    bf16* dst = A.dst + (size_t)mat * 16384 + ((ct * 4 + kc) * 4 + q) * 128 + m * 8;
    *(bf16x8*)dst = t;
}

// ---------------------------------------------------------------------------
// CSR build (counting sort by destination), fused across the 1-2 edge types
// of a destination group via gridDim.y. All init by kernels (graph-capture
// safe); atomics are 4B tickets only.
// ---------------------------------------------------------------------------
struct CsrArgs {
    const int* si[2];
    const int* di[2];
    int* ofs[2];
    int* tick[2];
    int* esrc[2];
    int* bsum[2];
    int E[2];
    int n1[2];   // nd + 1 (same nd within a group)
};

__global__ __launch_bounds__(256)
void csr_zero(CsrArgs A) {
    int t = blockIdx.y;
    int i = blockIdx.x * 256 + threadIdx.x;
    if (i < A.n1[t]) A.ofs[t][i] = 0;
}

__global__ __launch_bounds__(256)
void csr_hist(CsrArgs A) {
    int t = blockIdx.y;
    int E = A.E[t];
    const int* di = A.di[t];
    int* ofs = A.ofs[t];
    for (int i = blockIdx.x * 256 + threadIdx.x; i < E; i += gridDim.x * 256)
        atomicAdd(&ofs[di[i] + 1], 1);
}

// Inclusive scan, stage 1: per-block (2048 elems) scan + block totals.
__global__ __launch_bounds__(256)
void csr_scan_blocks(CsrArgs A) {
    __shared__ int lds[256];
    int ty = blockIdx.y;
    int n = A.n1[ty];
    int* a = A.ofs[ty];
    int* bsum = A.bsum[ty];
    int t = threadIdx.x;
    int base = blockIdx.x * 2048 + t * 8;
    int v[8];
    int run = 0;
#pragma unroll
    for (int j = 0; j < 8; ++j) {
        int idx = base + j;
        int x = (idx < n) ? a[idx] : 0;
        run += x;
        v[j] = run;
    }
    lds[t] = run;
    __syncthreads();
#pragma unroll
    for (int off = 1; off < 256; off <<= 1) {
        int x = (t >= off) ? lds[t - off] : 0;
        __syncthreads();
        lds[t] += x;
        __syncthreads();
    }
    int excl = t ? lds[t - 1] : 0;
#pragma unroll
    for (int j = 0; j < 8; ++j) {
        int idx = base + j;
        if (idx < n) a[idx] = v[j] + excl;
    }
    if (t == 255) bsum[blockIdx.x] = lds[255];
}

// Stage 2: exclusive scan of block totals (one block per type).
__global__ __launch_bounds__(256)
void csr_scan_bsums(CsrArgs A, int nb) {
    __shared__ int lds[256];
    int ty = blockIdx.x;
    int* bsum = A.bsum[ty];
    int t = threadIdx.x;
    int carry = 0;
    for (int base = 0; base < nb; base += 256) {
        int i = base + t;
        int v = (i < nb) ? bsum[i] : 0;
        lds[t] = v;
        __syncthreads();
#pragma unroll
        for (int off = 1; off < 256; off <<= 1) {
            int x = (t >= off) ? lds[t - off] : 0;
            __syncthreads();
            lds[t] += x;
            __syncthreads();
        }
        int excl = t ? lds[t - 1] : 0;
        if (i < nb) bsum[i] = excl + carry;
        carry += lds[255];
        __syncthreads();
    }
}

// Stage 3: add block offsets; init per-row tickets tick[d] = start(d).
__global__ __launch_bounds__(256)
void csr_scan_add(CsrArgs A) {
    int ty = blockIdx.y;
    int n = A.n1[ty];
    int* a = A.ofs[ty];
    const int* bsum = A.bsum[ty];
    int* tick = A.tick[ty];
    int i = blockIdx.x * 256 + threadIdx.x;
    if (i < n) {
        int v = a[i] + bsum[i >> 11];
        a[i] = v;
        if (i < n - 1) tick[i] = v;
    }
}

// Ticketed bucket fill: esrc[slot] = source id, grouped by destination.
// pos clamped: no state (even corrupt) can cause an OOB write.
__global__ __launch_bounds__(256)
void csr_fill(CsrArgs A) {
    int ty = blockIdx.y;
    int E = A.E[ty];
    const int* si = A.si[ty];
    const int* di = A.di[ty];
    int* tick = A.tick[ty];
    int* esrc = A.esrc[ty];
    for (int i = blockIdx.x * 256 + threadIdx.x; i < E; i += gridDim.x * 256) {
        int pos = atomicAdd(&tick[di[i]], 1);
        pos = pos < 0 ? 0 : (pos >= E ? E - 1 : pos);  // healthy path: no-op
        esrc[pos] = si[i];
    }
}

// ---------------------------------------------------------------------------
// Per-destination fused SAGE: for each of nc (1-2) contributions c,
//   y_c = x_dst@WLc^T + b_c + mean_{e in CSRc row}(x_srcc[e])@WRc^T
// then out_row = sum_c L2norm(y_c). Block = 4 waves; wave = 16 rows x 128
// cols, 8 col-tiles of mfma_f32_16x16x32_bf16. A1 (x_dst) loaded once and
// shared across contributions; each contribution's normalized result is
// accumulated in registers (no global read-modify-write). B fragments are
// single 16B bf16x8 loads from the pre-converted fragment buffer.
// ---------------------------------------------------------------------------
struct SageArgs {
    const float* xdst;
    float* out;
    int nd;
    int nc;
    const float* xsrc[2];
    const int* ofs[2];
    const int* esrc[2];
    const bf16* wf[2];      // frag-ordered WL|WR, 64 KB per type
    const float* bias[2];
    int nsrc[2];
    int E[2];
};

__global__ __launch_bounds__(256)
void sage_fused(SageArgs A) {
    int lane = threadIdx.x & 63;
    int wave = threadIdx.x >> 6;
    int m = lane & 15;   // A row within tile / C col within tile
    int q = lane >> 4;   // quad
    int nd = A.nd;
    int r0 = blockIdx.x * 64 + wave * 16;   // row base
    int rl = min(r0 + m, nd - 1);           // clamped load row

    // A1 fragments: x_dst rows (fp32 -> bf16), shared by all contributions.
    bf16x8 a1[4];
    const f32x4* xrow = (const f32x4*)(A.xdst + (size_t)rl * 128);
#pragma unroll
    for (int kc = 0; kc < 4; ++kc)
        a1[kc] = pack_bf16x8(xrow[kc * 8 + q * 2], xrow[kc * 8 + q * 2 + 1]);

    float ysum[8][4];
#pragma unroll
    for (int ct = 0; ct < 8; ++ct)
#pragma unroll
        for (int r = 0; r < 4; ++r) ysum[ct][r] = 0.f;

    for (int c = 0; c < A.nc; ++c) {
        const int* ofs  = A.ofs[c];
        const int* esrc = A.esrc[c];
        const float* xsrc = A.xsrc[c];
        int nsrc = A.nsrc[c];
        int Et   = A.E[c];

        // In-register CSR mean aggregation (lane gathers its 32 columns);
        // 2-edge unroll for memory-level parallelism. Indices clamped.
        int start = ofs[rl];
        int end   = ofs[rl + 1];
        start = start < 0 ? 0 : (start > Et ? Et : start);
        end   = end < start ? start : (end > Et ? Et : end);
        f32x4 aglo[4], aghi[4];
#pragma unroll
        for (int kc = 0; kc < 4; ++kc) {
            aglo[kc] = (f32x4){0.f, 0.f, 0.f, 0.f};
            aghi[kc] = (f32x4){0.f, 0.f, 0.f, 0.f};
        }
        int e = start;
        for (; e + 2 <= end; e += 2) {
            int s0 = esrc[e];
            int s1 = esrc[e + 1];
            s0 = s0 < 0 ? 0 : (s0 >= nsrc ? nsrc - 1 : s0);
            s1 = s1 < 0 ? 0 : (s1 >= nsrc ? nsrc - 1 : s1);
            const f32x4* p0 = (const f32x4*)(xsrc + (size_t)s0 * 128 + q * 8);
            const f32x4* p1 = (const f32x4*)(xsrc + (size_t)s1 * 128 + q * 8);
#pragma unroll
            for (int kc = 0; kc < 4; ++kc) {
                f32x4 u0 = p0[kc * 8], v0 = p0[kc * 8 + 1];
                f32x4 u1 = p1[kc * 8], v1 = p1[kc * 8 + 1];
                aglo[kc] += u0 + u1;
                aghi[kc] += v0 + v1;
            }
        }
        if (e < end) {
            int s0 = esrc[e];
            s0 = s0 < 0 ? 0 : (s0 >= nsrc ? nsrc - 1 : s0);
            const f32x4* p0 = (const f32x4*)(xsrc + (size_t)s0 * 128 + q * 8);
#pragma unroll
            for (int kc = 0; kc < 4; ++kc) {
                aglo[kc] += p0[kc * 8];
                aghi[kc] += p0[kc * 8 + 1];
            }
        }
        float invc = 1.0f / (float)max(end - start, 1);
        bf16x8 a2[4];
#pragma unroll
        for (int kc = 0; kc < 4; ++kc) {
            bf16x8 t;
#pragma unroll
            for (int j = 0; j < 4; ++j) {
                t[j]     = (__bf16)(aglo[kc][j] * invc);
                t[4 + j] = (__bf16)(aghi[kc][j] * invc);
            }
            a2[kc] = t;
        }

        // 8 col-tiles; B fragments are direct 16B bf16x8 loads.
        const bf16x8* wf = (const bf16x8*)A.wf[c];
        int fb = q * 16 + m;
        f32x4 acc[8];
#pragma unroll
        for (int ct = 0; ct < 8; ++ct) {
            f32x4 cc = {0.f, 0.f, 0.f, 0.f};
#pragma unroll
            for (int kc = 0; kc < 4; ++kc) {
                bf16x8 bl = wf[(ct * 4 + kc) * 64 + fb];
                bf16x8 br = wf[2048 + (ct * 4 + kc) * 64 + fb];
                cc = __builtin_amdgcn_mfma_f32_16x16x32_bf16(a1[kc], bl, cc, 0, 0, 0);
                cc = __builtin_amdgcn_mfma_f32_16x16x32_bf16(a2[kc], br, cc, 0, 0, 0);
            }
            acc[ct] = cc;
        }

        // +bias, per-row L2 norm (row lives across the 16-lane group),
        // accumulate normalized result into ysum registers.
        const float* bias = A.bias[c];
        float ss[4] = {0.f, 0.f, 0.f, 0.f};
#pragma unroll
        for (int ct = 0; ct < 8; ++ct) {
            float bb = bias[ct * 16 + m];
#pragma unroll
            for (int r = 0; r < 4; ++r) {
                float v = acc[ct][r] + bb;
                acc[ct][r] = v;
                ss[r] += v * v;
            }
        }
#pragma unroll
        for (int off = 1; off < 16; off <<= 1) {
#pragma unroll
            for (int r = 0; r < 4; ++r) ss[r] += __shfl_xor(ss[r], off);
        }
        float sc[4];
#pragma unroll
        for (int r = 0; r < 4; ++r) sc[r] = 1.0f / fmaxf(sqrtf(ss[r]), 1e-12f);
#pragma unroll
        for (int ct = 0; ct < 8; ++ct)
#pragma unroll
            for (int r = 0; r < 4; ++r) ysum[ct][r] += acc[ct][r] * sc[r];
    }

    // Single store pass (no read-modify-write of global output).
#pragma unroll
    for (int r = 0; r < 4; ++r) {
        int orow = r0 + q * 4 + r;  // C/D: row = quad*4 + reg
        if (orow < nd) {
            float* op = A.out + (size_t)orow * 128 + m;
#pragma unroll
            for (int ct = 0; ct < 8; ++ct) op[ct * 16] = ysum[ct][r];
        }
    }
}

extern "C" void kernel_launch(void* const* d_in, const int* in_sizes, int n_in,
                              void* d_out, int out_size, void* d_ws, size_t ws_size,
                              hipStream_t stream) {
    const int D = 128;
    const float* x_article = (const float*)d_in[0];
    const float* x_entity  = (const float*)d_in[1];
    const float* x_fact    = (const float*)d_in[2];
    int NA = in_sizes[0] / D;
    int NE = in_sizes[1] / D;
    int NF = in_sizes[2] / D;

    const int* si[5];
    const int* di[5];
    for (int i = 0; i < 5; ++i) {
        si[i] = (const int*)d_in[3 + 2 * i];
        di[i] = (const int*)d_in[4 + 2 * i];
    }
    const float *wl[5], *bia[5], *wr[5];
    for (int i = 0; i < 5; ++i) {
        wl[i]  = (const float*)d_in[13 + 3 * i];
        bia[i] = (const float*)d_in[14 + 3 * i];
        wr[i]  = (const float*)d_in[15 + 3 * i];
    }

    float* outp = (float*)d_out;
    float* out_article = outp;
    float* out_entity  = outp + (size_t)NA * D;
    float* out_fact    = outp + (size_t)(NA + NE) * D;

    // EDGE_TYPES: (art->ent), (art->fact), (ent->art), (ent->fact), (fact->ent)
    const float* xsrc[5] = {x_article, x_article, x_entity, x_entity, x_fact};
    int nsrcs[5] = {NA, NA, NE, NE, NF};

    // Weight fragments (bf16, MFMA-fragment order): 64 KB per type at ws base.
    bf16* wfrag = (bf16*)d_ws;
    WConvArgs wa;
    for (int t = 0; t < 5; ++t) {
        wa.w[t * 2]     = wl[t];
        wa.w[t * 2 + 1] = wr[t];
    }
    wa.dst = wfrag;
    convert_w<<<dim3(8, 10), 256, 0, stream>>>(wa);

    int* csr_base = (int*)((char*)d_ws + (size_t)5 * 32768 * sizeof(bf16));

    // Destination groups: article <- {t2}; entity <- {t0,t4}; fact <- {t1,t3}.
    int grp_types[3][2] = {{2, -1}, {0, 4}, {1, 3}};
    int grp_nt[3] = {1, 2, 2};
    const float* grp_xdst[3] = {x_article, x_entity, x_fact};
    float* grp_out[3] = {out_article, out_entity, out_fact};
    int grp_nd[3] = {NA, NE, NF};

    for (int g = 0; g < 3; ++g) {
        int nt = grp_nt[g];
        int nd = grp_nd[g];
        int n1 = nd + 1;
        CsrArgs ca = {};
        SageArgs sa = {};
        int* p = csr_base;   // workspace reused per group (~6.5 MB max)
        int Emax = 0;
        for (int k = 0; k < nt; ++k) {
            int t = grp_types[g][k];
            int E = in_sizes[3 + 2 * t];
            ca.si[k] = si[t];
            ca.di[k] = di[t];
            ca.ofs[k]  = p; p += n1;
            ca.tick[k] = p; p += nd;
            ca.esrc[k] = p; p += E;
            ca.bsum[k] = p; p += 256;
            ca.E[k] = E;
            ca.n1[k] = n1;
            if (E > Emax) Emax = E;
            sa.xsrc[k] = xsrc[t];
            sa.ofs[k]  = ca.ofs[k];
            sa.esrc[k] = ca.esrc[k];
            sa.wf[k]   = wfrag + (size_t)t * 32768;
            sa.bias[k] = bia[t];
            sa.nsrc[k] = nsrcs[t];
            sa.E[k]    = E;
        }
        int blk = (n1 + 255) / 256;
        int nb  = (n1 + 2047) / 2048;
        csr_zero<<<dim3(blk, nt), 256, 0, stream>>>(ca);
        csr_hist<<<dim3(1024, nt), 256, 0, stream>>>(ca);
        csr_scan_blocks<<<dim3(nb, nt), 256, 0, stream>>>(ca);
        csr_scan_bsums<<<dim3(nt), 256, 0, stream>>>(ca, nb);
        csr_scan_add<<<dim3(blk, nt), 256, 0, stream>>>(ca);
        csr_fill<<<dim3(1024, nt), 256, 0, stream>>>(ca);

        sa.xdst = grp_xdst[g];
        sa.out  = grp_out[g];
        sa.nd   = nd;
        sa.nc   = nt;
        sage_fused<<<(nd + 63) / 64, 256, 0, stream>>>(sa);
    }
}